// Round 3
// baseline (769.324 us; speedup 1.0000x reference)
//
#include <hip/hip_runtime.h>
#include <hip/hip_bf16.h>
#include <stdint.h>

#define BATCH 512
#define PIX   196
#define EDIM  2048
#define DDIM  512
#define ADIM  512
#define MROWS (BATCH*PIX)   // 100352 = 784*128

#define BM 128
#define BN 128
#define BK 32
#define NKT (EDIM/BK)       // 64

typedef __attribute__((ext_vector_type(8))) short bf16x8;
typedef __attribute__((ext_vector_type(8))) float f32x8;
typedef __attribute__((ext_vector_type(8))) __bf16 bf16v8;
typedef __attribute__((ext_vector_type(4))) float f32x4;

#define GLL16(g, lptr) __builtin_amdgcn_global_load_lds( \
    (const __attribute__((address_space(1))) void*)(g),  \
    (__attribute__((address_space(3))) void*)(lptr), 16, 0, 0)

static __device__ __forceinline__ unsigned short f2bf(float f) {
  union { float f; uint32_t u; } v; v.f = f;
  uint32_t u = v.u;
  return (unsigned short)((u + 0x7FFFu + ((u >> 16) & 1u)) >> 16);  // RNE
}

// fp32x8 -> bf16x8 via compiler-selected v_cvt_pk_bf16_f32 (RNE)
static __device__ __forceinline__ bf16x8 cvt8(float4 a, float4 b) {
  f32x8 v = {a.x, a.y, a.z, a.w, b.x, b.y, b.z, b.w};
  bf16v8 c = __builtin_convertvector(v, bf16v8);
  bf16x8 r;
  __builtin_memcpy(&r, &c, 16);
  return r;
}

// ---------------- K0a: W_enc [2048][512] f32 -> Bt [512][2048] bf16 ----------
__global__ void k_transpose_wenc(const float* __restrict__ W,
                                 unsigned short* __restrict__ Bt) {
  __shared__ float tile[32][33];
  const int kt = blockIdx.x;            // 64 tiles over K
  const int nt = blockIdx.y;            // 16 tiles over N
  const int tx = threadIdx.x, ty = threadIdx.y;   // 32 x 8
#pragma unroll
  for (int j = 0; j < 4; j++)
    tile[ty + 8*j][tx] = W[(size_t)(kt*32 + ty + 8*j)*ADIM + nt*32 + tx];
  __syncthreads();
#pragma unroll
  for (int j = 0; j < 4; j++)
    Bt[(size_t)(nt*32 + ty + 8*j)*EDIM + kt*32 + tx] = f2bf(tile[tx][ty + 8*j]);
}

// ---------------- K0b: att2 = hidden @ W_dec + b_dec ------------------------
__global__ void k_att2(const float* __restrict__ H, const float* __restrict__ Wd,
                       const float* __restrict__ bd, float* __restrict__ att2) {
  __shared__ float h[DDIM];
  const int b = blockIdx.x;
  const int t = threadIdx.x;            // 256
  h[t]       = H[(size_t)b*DDIM + t];
  h[t + 256] = H[(size_t)b*DDIM + t + 256];
  __syncthreads();
  float a0 = 0.f, a1 = 0.f;
#pragma unroll 8
  for (int k = 0; k < DDIM; k++) {
    const float hv = h[k];
    a0 += hv * Wd[(size_t)k*ADIM + t];
    a1 += hv * Wd[(size_t)k*ADIM + t + 256];
  }
  att2[(size_t)b*ADIM + t]       = a0 + bd[t];
  att2[(size_t)b*ADIM + t + 256] = a1 + bd[t + 256];
}

// ---------------- K1: fused att1-GEMM + tanh + scores(partial) --------------
// grid 3136 (1D, XCD-swizzled, n-minor), 256 threads (4 waves, 2x2)
// 3-buffer LDS pipeline, prefetch depth 2, counted s_waitcnt vmcnt (T3/T4).
__global__ __launch_bounds__(256, 2) void k_gemm_scores(
    const float* __restrict__ enc,          // [M][2048] f32
    const unsigned short* __restrict__ Bt,  // [512][2048] bf16
    const float* __restrict__ b_enc,        // [512]
    const float* __restrict__ att2,         // [B][512]
    const float* __restrict__ W_full,       // [512]
    float* __restrict__ scores)             // [M] (pre-zeroed, atomicAdd)
{
  __shared__ float Asf[3][BM][BK];           // 48 KB, 16B-chunk XOR swizzle
  __shared__ unsigned short Bsb[3][BN][BK];  // 24 KB, linear
  __shared__ float sc[BM];

  const int t   = threadIdx.x;
  const int l   = t & 63;
  const int wid = t >> 6;
  const int wr  = wid >> 1, wc = wid & 1;

  // XCD swizzle (nwg=3136=8*392), n-minor: 4 N-tiles of one M-tile run
  // consecutively on the same XCD -> A-tile fetched once, reused from L2.
  const int orig = blockIdx.x;
  const int tile = (orig & 7) * 392 + (orig >> 3);
  const int bm0 = (tile >> 2) * BM;
  const int bn0 = (tile & 3) * BN;

  if (t < BM) sc[t] = 0.f;

  // A: 16KB fp32 tile = 1024 x 16B chunks; chunk c=(row=c>>3, cir=c&7);
  //    LDS chunk (row,cir) holds global k-chunk (cir ^ (row&7)).
  // B: 8KB bf16 tile = 512 chunks; linear.
  // GLL dest base is wave-uniform (j,wid); lane*16 is implicit.
#define STAGE(bufi, kt) do {                                                  \
    _Pragma("unroll")                                                         \
    for (int j = 0; j < 4; j++) {                                             \
      const int c   = j*256 + t;                                              \
      const int row = c >> 3;                                                 \
      const int cir = (c & 7) ^ (row & 7);                                    \
      GLL16(enc + (size_t)(bm0 + row)*EDIM + (kt)*BK + cir*4,                 \
            (char*)(&Asf[bufi][0][0]) + (j*4 + wid)*1024);                    \
    }                                                                         \
    _Pragma("unroll")                                                         \
    for (int j = 0; j < 2; j++) {                                             \
      const int c   = j*256 + t;                                              \
      const int row = c >> 2;                                                 \
      GLL16(Bt + (size_t)(bn0 + row)*EDIM + (kt)*BK + (c & 3)*8,              \
            (char*)(&Bsb[bufi][0][0]) + (j*4 + wid)*1024);                    \
    }                                                                         \
  } while (0)

  f32x4 acc[4][4] = {};

  STAGE(0, 0);
  STAGE(1, 1);
  STAGE(2, 2);

  for (int kt = 0; kt < NKT; kt++) {
    const int buf = kt - (kt / 3) * 3;   // kt % 3

    // buf's 6 loads done iff vmcnt <= 12 (tiles kt+1, kt+2 may be in flight)
    if (kt < NKT - 2)      asm volatile("s_waitcnt vmcnt(12)" ::: "memory");
    else if (kt == NKT - 2) asm volatile("s_waitcnt vmcnt(6)" ::: "memory");
    else                    asm volatile("s_waitcnt vmcnt(0)" ::: "memory");
    __builtin_amdgcn_s_barrier();

    bf16x8 af[4], bfr[4];
#pragma unroll
    for (int mi = 0; mi < 4; mi++) {
      const int r = wr*64 + mi*16 + (l & 15);
      const int g = (l >> 4) * 2;
      const float4 fa = *(const float4*)((const char*)&Asf[buf][0][0]
                            + r*128 + ((g    ) ^ (r & 7))*16);
      const float4 fb = *(const float4*)((const char*)&Asf[buf][0][0]
                            + r*128 + ((g + 1) ^ (r & 7))*16);
      af[mi] = cvt8(fa, fb);
    }
#pragma unroll
    for (int ni = 0; ni < 4; ni++)
      bfr[ni] = *(const bf16x8*)(&Bsb[buf][wc*64 + ni*16 + (l & 15)][(l >> 4) * 8]);

#pragma unroll
    for (int mi = 0; mi < 4; mi++)
#pragma unroll
      for (int ni = 0; ni < 4; ni++)
        acc[mi][ni] = __builtin_amdgcn_mfma_f32_16x16x32_bf16(af[mi], bfr[ni], acc[mi][ni], 0, 0, 0);

    asm volatile("s_waitcnt lgkmcnt(0)" ::: "memory");
    __builtin_amdgcn_s_barrier();

    if (kt + 3 < NKT) STAGE(buf, kt + 3);
  }

  // epilogue: scores partial = sum_cols tanh(acc + b_enc + att2) * W_full
  const int lr = l >> 4;       // 0..3
  const int lc = l & 15;
  float be[4], wf[4];
  int colv[4];
#pragma unroll
  for (int ni = 0; ni < 4; ni++) {
    colv[ni] = bn0 + wc*64 + ni*16 + lc;
    be[ni] = b_enc[colv[ni]];
    wf[ni] = W_full[colv[ni]];
  }
#pragma unroll
  for (int mi = 0; mi < 4; mi++) {
#pragma unroll
    for (int e = 0; e < 4; e++) {
      const int row_l = wr*64 + mi*16 + lr*4 + e;
      const unsigned gr = (unsigned)(bm0 + row_l);
      const unsigned b  = gr / 196u;
      float s = 0.f;
#pragma unroll
      for (int ni = 0; ni < 4; ni++) {
        const float v = acc[mi][ni][e] + be[ni] + att2[(size_t)b*ADIM + colv[ni]];
        s += tanhf(v) * wf[ni];
      }
      s += __shfl_xor(s, 1); s += __shfl_xor(s, 2);
      s += __shfl_xor(s, 4); s += __shfl_xor(s, 8);
      if (lc == 0) atomicAdd(&sc[row_l], s);
    }
  }
  __syncthreads();
  if (t < BM) atomicAdd(&scores[bm0 + t], sc[t]);
}

// ---------------- K2: softmax over P per batch (in place) -------------------
__global__ void k_softmax(float* __restrict__ sa) {   // [512][196]
  __shared__ float red[256];
  const int b = blockIdx.x, t = threadIdx.x;
  const float v = (t < PIX) ? sa[(size_t)b*PIX + t] : -1e30f;
  red[t] = v; __syncthreads();
  for (int s2 = 128; s2 > 0; s2 >>= 1) {
    if (t < s2) red[t] = fmaxf(red[t], red[t + s2]);
    __syncthreads();
  }
  const float m = red[0]; __syncthreads();
  const float e = (t < PIX) ? __expf(v - m) : 0.f;
  red[t] = e; __syncthreads();
  for (int s2 = 128; s2 > 0; s2 >>= 1) {
    if (t < s2) red[t] += red[t + s2];
    __syncthreads();
  }
  const float inv = 1.f / red[0];
  if (t < PIX) sa[(size_t)b*PIX + t] = e * inv;
}

// ---------------- K3: context = sum_p alpha[p] * enc[b][p][:] ---------------
__global__ __launch_bounds__(512) void k_context(
    const float* __restrict__ enc, const float* __restrict__ alpha,
    float* __restrict__ ctx) {
  __shared__ float al[PIX];
  const int b = blockIdx.x, t = threadIdx.x;
  if (t < PIX) al[t] = alpha[(size_t)b*PIX + t];
  __syncthreads();
  const float4* e4 = (const float4*)(enc + (size_t)b * PIX * EDIM);
  float4 acc = {0.f, 0.f, 0.f, 0.f};
#pragma unroll 4
  for (int p = 0; p < PIX; p++) {
    const float4 v = e4[(size_t)p * (EDIM/4) + t];
    const float a = al[p];
    acc.x += v.x * a; acc.y += v.y * a; acc.z += v.z * a; acc.w += v.w * a;
  }
  ((float4*)(ctx + (size_t)b * EDIM))[t] = acc;
}

// ---------------------------------------------------------------------------
extern "C" void kernel_launch(void* const* d_in, const int* in_sizes, int n_in,
                              void* d_out, int out_size, void* d_ws, size_t ws_size,
                              hipStream_t stream) {
  (void)in_sizes; (void)n_in; (void)out_size; (void)ws_size;
  const float* enc   = (const float*)d_in[0];
  const float* hid   = (const float*)d_in[1];
  const float* Wenc  = (const float*)d_in[2];
  const float* benc  = (const float*)d_in[3];
  const float* Wdec  = (const float*)d_in[4];
  const float* bdec  = (const float*)d_in[5];
  const float* Wfull = (const float*)d_in[6];
  // d_in[7] = b_full: softmax-invariant, unused.

  unsigned short* Bt = (unsigned short*)d_ws;                       // 2 MB
  float* att2 = (float*)((char*)d_ws + (size_t)ADIM * EDIM * 2);    // 1 MB
  float* ctx   = (float*)d_out;
  float* alpha = (float*)d_out + (size_t)BATCH * EDIM;              // scores live here

  hipMemsetAsync(alpha, 0, (size_t)MROWS * sizeof(float), stream);
  k_transpose_wenc<<<dim3(64, 16), dim3(32, 8), 0, stream>>>(Wenc, Bt);
  k_att2<<<BATCH, 256, 0, stream>>>(hid, Wdec, bdec, att2);
  k_gemm_scores<<<3136, 256, 0, stream>>>(enc, Bt, benc, att2, Wfull, alpha);
  k_softmax<<<BATCH, 256, 0, stream>>>(alpha);
  k_context<<<BATCH, 512, 0, stream>>>(enc, alpha, ctx);
}

// Round 4
// 652.341 us; speedup vs baseline: 1.1793x; 1.1793x over previous
//
#include <hip/hip_runtime.h>
#include <hip/hip_bf16.h>
#include <stdint.h>

#define BATCH 512
#define PIX   196
#define EDIM  2048
#define DDIM  512
#define ADIM  512
#define MROWS (BATCH*PIX)   // 100352 = 784*128

#define BM 128
#define BN 128
#define BK 32
#define NKT (EDIM/BK)       // 64

typedef __attribute__((ext_vector_type(8))) short bf16x8;
typedef __attribute__((ext_vector_type(8))) float f32x8;
typedef __attribute__((ext_vector_type(8))) __bf16 bf16v8;
typedef __attribute__((ext_vector_type(4))) float f32x4;

#define GLL16(g, lptr) __builtin_amdgcn_global_load_lds( \
    (const __attribute__((address_space(1))) void*)(g),  \
    (__attribute__((address_space(3))) void*)(lptr), 16, 0, 0)

static __device__ __forceinline__ unsigned short f2bf(float f) {
  union { float f; uint32_t u; } v; v.f = f;
  uint32_t u = v.u;
  return (unsigned short)((u + 0x7FFFu + ((u >> 16) & 1u)) >> 16);  // RNE
}

// fp32x8 -> bf16x8 via compiler-selected v_cvt_pk_bf16_f32 (RNE)
static __device__ __forceinline__ bf16x8 cvt8(float4 a, float4 b) {
  f32x8 v = {a.x, a.y, a.z, a.w, b.x, b.y, b.z, b.w};
  bf16v8 c = __builtin_convertvector(v, bf16v8);
  bf16x8 r;
  __builtin_memcpy(&r, &c, 16);
  return r;
}

// ---------------- K0a: W_enc [2048][512] f32 -> Bt [512][2048] bf16 ----------
__global__ void k_transpose_wenc(const float* __restrict__ W,
                                 unsigned short* __restrict__ Bt) {
  __shared__ float tile[32][33];
  const int kt = blockIdx.x;            // 64 tiles over K
  const int nt = blockIdx.y;            // 16 tiles over N
  const int tx = threadIdx.x, ty = threadIdx.y;   // 32 x 8
#pragma unroll
  for (int j = 0; j < 4; j++)
    tile[ty + 8*j][tx] = W[(size_t)(kt*32 + ty + 8*j)*ADIM + nt*32 + tx];
  __syncthreads();
#pragma unroll
  for (int j = 0; j < 4; j++)
    Bt[(size_t)(nt*32 + ty + 8*j)*EDIM + kt*32 + tx] = f2bf(tile[tx][ty + 8*j]);
}

// ---------------- K0b: att2 = hidden @ W_dec + b_dec ------------------------
__global__ void k_att2(const float* __restrict__ H, const float* __restrict__ Wd,
                       const float* __restrict__ bd, float* __restrict__ att2) {
  __shared__ float h[DDIM];
  const int b = blockIdx.x;
  const int t = threadIdx.x;            // 256
  h[t]       = H[(size_t)b*DDIM + t];
  h[t + 256] = H[(size_t)b*DDIM + t + 256];
  __syncthreads();
  float a0 = 0.f, a1 = 0.f;
#pragma unroll 8
  for (int k = 0; k < DDIM; k++) {
    const float hv = h[k];
    a0 += hv * Wd[(size_t)k*ADIM + t];
    a1 += hv * Wd[(size_t)k*ADIM + t + 256];
  }
  att2[(size_t)b*ADIM + t]       = a0 + bd[t];
  att2[(size_t)b*ADIM + t + 256] = a1 + bd[t + 256];
}

// ---------------- K1: fused att1-GEMM + tanh + scores(partial) --------------
// grid 3136 (1D, XCD-swizzled, n-minor), 256 threads (4 waves, 2x2)
// 2-buffer LDS, __syncthreads 2-phase (3 blocks/CU), explicit unroll-by-2 so
// ALL LDS addresses are loop-invariant VGPRs + compile-time immediates.
__global__ __launch_bounds__(256, 3) void k_gemm_scores(
    const float* __restrict__ enc,          // [M][2048] f32
    const unsigned short* __restrict__ Bt,  // [512][2048] bf16
    const float* __restrict__ b_enc,        // [512]
    const float* __restrict__ att2,         // [B][512]
    const float* __restrict__ W_full,       // [512]
    float* __restrict__ scores)             // [M] (pre-zeroed, atomicAdd)
{
  __shared__ float Asf[2][BM][BK];           // 32 KB, 16B-chunk XOR swizzle
  __shared__ unsigned short Bsb[2][BN][BK];  // 16 KB, linear
  __shared__ float sc[BM];

  const int t   = threadIdx.x;
  const int l   = t & 63;
  const int wid = t >> 6;
  const int wr  = wid >> 1, wc = wid & 1;

  // XCD swizzle (nwg=3136=8*392), n-minor: 4 N-tiles of one M-tile run
  // consecutively on the same XCD -> A-tile fetched once, reused from L2.
  const int orig = blockIdx.x;
  const int tile = (orig & 7) * 392 + (orig >> 3);
  const int bm0 = (tile >> 2) * BM;
  const int bn0 = (tile & 3) * BN;

  if (t < BM) sc[t] = 0.f;

  // Staging source pointers (advance by kt*BK elements each step).
  // A: 16KB fp32 tile = 1024 x 16B chunks; chunk c=(row=c>>3, q=c&7);
  //    LDS chunk (row,q) holds global k-chunk (q ^ (row&7)).
  const float* srcA[4];
  const unsigned short* srcB[2];
#pragma unroll
  for (int j = 0; j < 4; j++) {
    const int row = j*32 + (t >> 3);
    const int cir = (t & 7) ^ (row & 7);
    srcA[j] = enc + (size_t)(bm0 + row)*EDIM + cir*4;
  }
#pragma unroll
  for (int j = 0; j < 2; j++) {
    const int row = j*64 + (t >> 2);
    srcB[j] = Bt + (size_t)(bn0 + row)*EDIM + (t & 3)*8;
  }

#define STAGE(buf, kt) do {                                                   \
    _Pragma("unroll")                                                         \
    for (int j = 0; j < 4; j++)                                               \
      GLL16(srcA[j] + (size_t)(kt)*BK,                                        \
            (char*)Asf + (buf)*16384 + (j*4 + wid)*1024);                     \
    _Pragma("unroll")                                                         \
    for (int j = 0; j < 2; j++)                                               \
      GLL16(srcB[j] + (size_t)(kt)*BK,                                        \
            (char*)Bsb + (buf)*8192 + (j*4 + wid)*1024);                      \
  } while (0)

  // Loop-invariant LDS read base addresses (byte offsets); mi/ni/buf are
  // compile-time immediates on the ds_read.
  const char* Ab = (const char*)Asf;
  const char* Bb = (const char*)Bsb;
  const int l15 = l & 15, hi = l >> 4;
  const int sA  = l15 & 7;                       // = (row & 7) for A reads
  const int addrA0 = (wr*64 + l15)*128 + (((hi*2)    ) ^ sA)*16;
  const int addrA1 = (wr*64 + l15)*128 + (((hi*2) + 1) ^ sA)*16;
  const int addrB  = (wc*64 + l15)*64 + hi*16;

  f32x4 acc[4][4] = {};

#define COMPUTE(buf) do {                                                     \
    bf16x8 af[4], bfr[4];                                                     \
    _Pragma("unroll")                                                         \
    for (int mi = 0; mi < 4; mi++) {                                          \
      const float4 fa = *(const float4*)(Ab + (buf)*16384 + mi*2048 + addrA0);\
      const float4 fb = *(const float4*)(Ab + (buf)*16384 + mi*2048 + addrA1);\
      af[mi] = cvt8(fa, fb);                                                  \
    }                                                                         \
    _Pragma("unroll")                                                         \
    for (int ni = 0; ni < 4; ni++)                                            \
      bfr[ni] = *(const bf16x8*)(Bb + (buf)*8192 + ni*1024 + addrB);          \
    _Pragma("unroll")                                                         \
    for (int mi = 0; mi < 4; mi++)                                            \
      _Pragma("unroll")                                                       \
      for (int ni = 0; ni < 4; ni++)                                          \
        acc[mi][ni] = __builtin_amdgcn_mfma_f32_16x16x32_bf16(                \
            af[mi], bfr[ni], acc[mi][ni], 0, 0, 0);                           \
  } while (0)

  STAGE(0, 0);
  __syncthreads();

  for (int kt = 0; kt < NKT; kt += 2) {
    STAGE(1, kt + 1);
    COMPUTE(0);
    __syncthreads();
    if (kt + 2 < NKT) STAGE(0, kt + 2);
    COMPUTE(1);
    __syncthreads();
  }

  // epilogue: scores partial = sum_cols tanh(acc + b_enc + att2) * W_full
  const int lr = hi;           // 0..3
  const int lc = l15;
  float be[4], wf[4];
  int colv[4];
#pragma unroll
  for (int ni = 0; ni < 4; ni++) {
    colv[ni] = bn0 + wc*64 + ni*16 + lc;
    be[ni] = b_enc[colv[ni]];
    wf[ni] = W_full[colv[ni]];
  }
#pragma unroll
  for (int mi = 0; mi < 4; mi++) {
#pragma unroll
    for (int e = 0; e < 4; e++) {
      const int row_l = wr*64 + mi*16 + lr*4 + e;
      const unsigned gr = (unsigned)(bm0 + row_l);
      const unsigned b  = gr / 196u;
      float s = 0.f;
#pragma unroll
      for (int ni = 0; ni < 4; ni++) {
        const float v = acc[mi][ni][e] + be[ni] + att2[(size_t)b*ADIM + colv[ni]];
        s += tanhf(v) * wf[ni];
      }
      s += __shfl_xor(s, 1); s += __shfl_xor(s, 2);
      s += __shfl_xor(s, 4); s += __shfl_xor(s, 8);
      if (lc == 0) atomicAdd(&sc[row_l], s);
    }
  }
  __syncthreads();
  if (t < BM) atomicAdd(&scores[bm0 + t], sc[t]);
}

// ---------------- K2: softmax over P per batch (in place) -------------------
__global__ void k_softmax(float* __restrict__ sa) {   // [512][196]
  __shared__ float red[256];
  const int b = blockIdx.x, t = threadIdx.x;
  const float v = (t < PIX) ? sa[(size_t)b*PIX + t] : -1e30f;
  red[t] = v; __syncthreads();
  for (int s2 = 128; s2 > 0; s2 >>= 1) {
    if (t < s2) red[t] = fmaxf(red[t], red[t + s2]);
    __syncthreads();
  }
  const float m = red[0]; __syncthreads();
  const float e = (t < PIX) ? __expf(v - m) : 0.f;
  red[t] = e; __syncthreads();
  for (int s2 = 128; s2 > 0; s2 >>= 1) {
    if (t < s2) red[t] += red[t + s2];
    __syncthreads();
  }
  const float inv = 1.f / red[0];
  if (t < PIX) sa[(size_t)b*PIX + t] = e * inv;
}

// ---------------- K3: context = sum_p alpha[p] * enc[b][p][:] ---------------
__global__ __launch_bounds__(512) void k_context(
    const float* __restrict__ enc, const float* __restrict__ alpha,
    float* __restrict__ ctx) {
  __shared__ float al[PIX];
  const int b = blockIdx.x, t = threadIdx.x;
  if (t < PIX) al[t] = alpha[(size_t)b*PIX + t];
  __syncthreads();
  const float4* e4 = (const float4*)(enc + (size_t)b * PIX * EDIM);
  float4 acc = {0.f, 0.f, 0.f, 0.f};
#pragma unroll 4
  for (int p = 0; p < PIX; p++) {
    const float4 v = e4[(size_t)p * (EDIM/4) + t];
    const float a = al[p];
    acc.x += v.x * a; acc.y += v.y * a; acc.z += v.z * a; acc.w += v.w * a;
  }
  ((float4*)(ctx + (size_t)b * EDIM))[t] = acc;
}

// ---------------------------------------------------------------------------
extern "C" void kernel_launch(void* const* d_in, const int* in_sizes, int n_in,
                              void* d_out, int out_size, void* d_ws, size_t ws_size,
                              hipStream_t stream) {
  (void)in_sizes; (void)n_in; (void)out_size; (void)ws_size;
  const float* enc   = (const float*)d_in[0];
  const float* hid   = (const float*)d_in[1];
  const float* Wenc  = (const float*)d_in[2];
  const float* benc  = (const float*)d_in[3];
  const float* Wdec  = (const float*)d_in[4];
  const float* bdec  = (const float*)d_in[5];
  const float* Wfull = (const float*)d_in[6];
  // d_in[7] = b_full: softmax-invariant, unused.

  unsigned short* Bt = (unsigned short*)d_ws;                       // 2 MB
  float* att2 = (float*)((char*)d_ws + (size_t)ADIM * EDIM * 2);    // 1 MB
  float* ctx   = (float*)d_out;
  float* alpha = (float*)d_out + (size_t)BATCH * EDIM;              // scores live here

  hipMemsetAsync(alpha, 0, (size_t)MROWS * sizeof(float), stream);
  k_transpose_wenc<<<dim3(64, 16), dim3(32, 8), 0, stream>>>(Wenc, Bt);
  k_att2<<<BATCH, 256, 0, stream>>>(hid, Wdec, bdec, att2);
  k_gemm_scores<<<3136, 256, 0, stream>>>(enc, Bt, benc, att2, Wfull, alpha);
  k_softmax<<<BATCH, 256, 0, stream>>>(alpha);
  k_context<<<BATCH, 512, 0, stream>>>(enc, alpha, ctx);
}